// Round 1
// 638.999 us; speedup vs baseline: 1.1465x; 1.1465x over previous
//
#include <hip/hip_runtime.h>
#include <hip/hip_bf16.h>

typedef __bf16 bf16_t;
typedef __bf16 bf16x8 __attribute__((ext_vector_type(8)));
typedef __bf16 bf16x4 __attribute__((ext_vector_type(4)));
typedef float f32x4 __attribute__((ext_vector_type(4)));

// ---------------------------------------------------------------------------
// Sizes (fixed): B = 16384, D = H = 512
//   A_big : [B][2048] bf16 = [x_re | x_im | h_re | h_im]
//   W1t   : [3072][2048] bf16 (B^T layout). Columns: [0,1024) z (K=2048),
//           [1024,2048) r (K=2048), [2048,3072) px2 (K=1024). re/im interleaved.
//   W2t   : [1024][1024] bf16, ph columns interleaved, K=1024 over [rh_re|rh_im]
//   A2    : [B][1024] bf16 = [rh_re | rh_im]
//   zbuf  : [B][1024] bf16 interleaved (z in [0,1]; bf16 quant <= 4e-3, safe)
//   t (= px2+bx2+bh2) staged fp32 in d_out, overwritten by final in GEMM2.
// ---------------------------------------------------------------------------

__device__ __forceinline__ void gl_lds16(const bf16_t* g, bf16_t* l) {
  __builtin_amdgcn_global_load_lds(
      (const __attribute__((address_space(1))) void*)g,
      (__attribute__((address_space(3))) void*)l, 16, 0, 0);
}

__device__ __forceinline__ float fast_sigmoid(float x) {
  return 1.0f / (1.0f + __expf(-x));
}

// ---------------------------------------------------------------------------
__global__ void pack_A(const float* __restrict__ x_re, const float* __restrict__ x_im,
                       const float* __restrict__ h_re, const float* __restrict__ h_im,
                       bf16_t* __restrict__ A) {
  int q = blockIdx.x * blockDim.x + threadIdx.x;   // 8388608 quads total
  int i4 = q << 2;
  int b = i4 >> 11;
  int k = i4 & 2047;
  int seg = k >> 9;
  int off = k & 511;
  const float* s = (seg == 0) ? x_re : (seg == 1) ? x_im : (seg == 2) ? h_re : h_im;
  const float4 v = *(const float4*)(s + (size_t)b * 512 + off);
  bf16x4 o = { (bf16_t)v.x, (bf16_t)v.y, (bf16_t)v.z, (bf16_t)v.w };
  *(bf16x4*)(A + (size_t)b * 2048 + k) = o;
}

// ---------------------------------------------------------------------------
__global__ void pack_W(const float* __restrict__ Wx_re, const float* __restrict__ Wx_im,
                       const float* __restrict__ Wh_re, const float* __restrict__ Wh_im,
                       bf16_t* __restrict__ W1t, bf16_t* __restrict__ W2t) {
  int q = blockIdx.x * blockDim.x + threadIdx.x;   // 1572864 quads total
  int n, k2, g, j, p;
  const float *Wre, *Wim;
  bf16_t* dst;
  if (q < 1048576) {                       // W1t rows [0,2048): z and r, k2 in [0,2048)
    n = q >> 9; k2 = (q & 511) << 2;
    g = n >> 10; j = (n & 1023) >> 1; p = n & 1;
    int pair = k2 >> 10;                   // 0: x-part (Wx), 1: h-part (Wh)
    Wre = pair ? Wh_re : Wx_re;
    Wim = pair ? Wh_im : Wx_im;
    dst = W1t + (size_t)n * 2048 + k2;
  } else if (q < 1048576 + 262144) {       // W1t rows [2048,3072): px2, k2 in [0,1024)
    int q2 = q - 1048576;
    n = 2048 + (q2 >> 8); k2 = (q2 & 255) << 2;
    g = 2; j = (n - 2048) >> 1; p = n & 1;
    Wre = Wx_re; Wim = Wx_im;
    dst = W1t + (size_t)n * 2048 + k2;
  } else {                                 // W2t rows [0,1024), k2 in [0,1024)
    int q3 = q - (1048576 + 262144);
    n = q3 >> 8; k2 = (q3 & 255) << 2;
    g = 2; j = n >> 1; p = n & 1;
    Wre = Wh_re; Wim = Wh_im;
    dst = W2t + (size_t)n * 1024 + k2;
  }
  int klocal = k2 & 1023;
  int half = klocal >> 9;                  // 0: real-operand half, 1: imag-operand half
  int off = klocal & 511;
  size_t sidx = ((size_t)g * 512 + j) * 512 + off;
  const float* s = (half == 0) ? (p ? Wim : Wre) : (p ? Wre : Wim);
  float sgn = (half == 1 && p == 0) ? -1.0f : 1.0f;
  float4 v = *(const float4*)(s + sidx);
  bf16x4 o = { (bf16_t)(sgn * v.x), (bf16_t)(sgn * v.y),
               (bf16_t)(sgn * v.z), (bf16_t)(sgn * v.w) };
  *(bf16x4*)dst = o;
}

// ---------------------------------------------------------------------------
// 256x256 tile, BK=64, 512 threads (8 waves, 2M x 4N; per-wave 128x64 output).
// 2 LDS buffers (2 x (A 32KB + B 32KB) = 128 KiB), 4 cluster-phases per K-tile:
//   c0=(mh0,kk0) c1=(mh1,kk0) c2=(mh0,kk1) c3=(mh1,kk1), 16 MFMA each.
// ds_reads for cluster c are issued in phase c-1 (c0+c1 both in phase 0), so
// the LDS read-drain overlaps the previous MFMA cluster (compiler emits
// counted lgkmcnt). Staging is sweep-granular (8 sweeps of 8KB per K-tile,
// 2 gl_lds16/thread/phase): tile t+1's {A1,A3}/{B0,B1}/{B2,B3} in phases
// 0/1/2, tile t+2's {A0,A2} in phase 3 (legal: sweeps 0,2 of the current
// buffer are last read in phase 2, barrier-separated). Boundary wait is a
// COUNTED vmcnt(2) (tile t+2's first pair stays in flight) -> staging never
// drains to 0 in steady state. setprio(1) wraps each MFMA cluster (T5).
// LDS swizzle: 16B-chunk c ^= (r&7) within each 128B row, applied on the
// global SOURCE address (gl_lds writes linearly) and on the ds_read address
// (same involution both sides) -> conflict-free b128 reads.
// Grid decode: xcd-chunked bijective swizzle; each CU gets exactly one
// z (32 K-tiles) + one r (32) + one px2 (16) block in MODE 1.
template <int MODE>
__launch_bounds__(512, 2)
__global__ void gemm_fused(const bf16_t* __restrict__ A, const bf16_t* __restrict__ W,
                           int LDA, int LDW,
                           bf16_t* __restrict__ zbuf, bf16_t* __restrict__ A2,
                           float* __restrict__ outbuf,
                           const float* __restrict__ h_re, const float* __restrict__ h_im,
                           const float* __restrict__ bx_re, const float* __restrict__ bx_im,
                           const float* __restrict__ bh_re, const float* __restrict__ bh_im) {
  __shared__ __align__(16) bf16_t As[2][256 * 64];
  __shared__ __align__(16) bf16_t Bs[2][256 * 64];

  const int bid = blockIdx.x;
  const int xcd = bid & 7;
  const int idx = bid >> 3;               // MODE1: 0..95, MODE2: 0..31
  const int ntile = idx >> 3;             // MODE1: 0..11, MODE2: 0..3
  const int mtile = (xcd << 3) + (idx & 7);  // 0..63
  const int m0 = mtile * 256;
  const int n0 = ntile * 256;
  const int region = (MODE == 1) ? (ntile >> 2) : 0;    // 0:z 1:r 2:px2
  const int KEND = (MODE == 1) ? ((region < 2) ? 2048 : 1024) : 1024;
  const int nKT = KEND >> 6;              // K-tiles of 64

  const int tid = threadIdx.x;
  const int lane = tid & 63;
  const int w = tid >> 6;                 // 0..7
  const int wr = w >> 2;                  // 0..1 (M)
  const int wc = w & 3;                   // 0..3 (N)

  // staging: sweep s covers rows [64s, 64s+64); thread -> (row rb, chunk cc)
  const int rb = tid >> 3;                // 0..63
  const int cc = tid & 7;                 // 16B chunk within 128B row
  const int cs = cc ^ (rb & 7);           // source-side swizzle
  const bf16_t* Ag = A + (size_t)(m0 + rb) * LDA + cs * 8;
  const bf16_t* Wg = W + (size_t)(n0 + rb) * LDW + cs * 8;

#define STAGE_A(s, bufi, kt2) \
  gl_lds16(Ag + (size_t)(s) * 64 * LDA + (kt2) * 64, &As[bufi][tid * 8 + (s) * 4096])
#define STAGE_B(s, bufi, kt2) \
  gl_lds16(Wg + (size_t)(s) * 64 * LDW + (kt2) * 64, &Bs[bufi][tid * 8 + (s) * 4096])

  const int quad = lane >> 4, lrow = lane & 15;
  int aOff[8], bOff[4];                   // kk0 offsets; kk1 = off ^ 32
#pragma unroll
  for (int mt = 0; mt < 8; ++mt) {
    const int r = wr * 128 + mt * 16 + lrow;
    aOff[mt] = r * 64 + ((quad ^ (r & 7)) << 3);
  }
#pragma unroll
  for (int nt = 0; nt < 4; ++nt) {
    const int r = wc * 64 + nt * 16 + lrow;
    bOff[nt] = r * 64 + ((quad ^ (r & 7)) << 3);
  }

  f32x4 acc[8][4] = {};

  // prologue: tile 0 fully (8 loads, oldest) + tile 1 {A0,A2} (2 loads)
#pragma unroll
  for (int s = 0; s < 4; ++s) STAGE_A(s, 0, 0);
#pragma unroll
  for (int s = 0; s < 4; ++s) STAGE_B(s, 0, 0);
  STAGE_A(0, 1, 1);
  STAGE_A(2, 1, 1);
  asm volatile("s_waitcnt vmcnt(2)" ::: "memory");
  __builtin_amdgcn_s_barrier();

  for (int kt = 0; kt < nKT; ++kt) {
    const int b = kt & 1;
    const bf16_t* Ab = As[b];
    const bf16_t* Bb = Bs[b];
    const bool s1 = (kt + 1 < nKT);
    const bool s2 = (kt + 2 < nKT);

    bf16x8 bk0[4], bk1[4], aA[4], aB[4], aC[4], aD[4];

    // ---- phase 0: reads for c0 (A03k0 + Bk0) and c1 (A47k0); MFMA c0 ----
#pragma unroll
    for (int nt = 0; nt < 4; ++nt) bk0[nt] = *(const bf16x8*)(Bb + bOff[nt]);
#pragma unroll
    for (int i = 0; i < 4; ++i) aA[i] = *(const bf16x8*)(Ab + aOff[i]);
#pragma unroll
    for (int i = 0; i < 4; ++i) aB[i] = *(const bf16x8*)(Ab + aOff[4 + i]);
    if (s1) { STAGE_A(1, b ^ 1, kt + 1); STAGE_A(3, b ^ 1, kt + 1); }
    asm volatile("" ::: "memory");
    __builtin_amdgcn_s_barrier();
    __builtin_amdgcn_s_setprio(1);
#pragma unroll
    for (int i = 0; i < 4; ++i)
#pragma unroll
      for (int nt = 0; nt < 4; ++nt)
        acc[i][nt] = __builtin_amdgcn_mfma_f32_16x16x32_bf16(aA[i], bk0[nt], acc[i][nt], 0, 0, 0);
    __builtin_amdgcn_s_setprio(0);
    __builtin_amdgcn_s_barrier();

    // ---- phase 1: reads for c2 (A03k1 + Bk1); MFMA c1 ----
#pragma unroll
    for (int i = 0; i < 4; ++i) aC[i] = *(const bf16x8*)(Ab + (aOff[i] ^ 32));
#pragma unroll
    for (int nt = 0; nt < 4; ++nt) bk1[nt] = *(const bf16x8*)(Bb + (bOff[nt] ^ 32));
    if (s1) { STAGE_B(0, b ^ 1, kt + 1); STAGE_B(1, b ^ 1, kt + 1); }
    asm volatile("" ::: "memory");
    __builtin_amdgcn_s_barrier();
    __builtin_amdgcn_s_setprio(1);
#pragma unroll
    for (int i = 0; i < 4; ++i)
#pragma unroll
      for (int nt = 0; nt < 4; ++nt)
        acc[4 + i][nt] = __builtin_amdgcn_mfma_f32_16x16x32_bf16(aB[i], bk0[nt], acc[4 + i][nt], 0, 0, 0);
    __builtin_amdgcn_s_setprio(0);
    __builtin_amdgcn_s_barrier();

    // ---- phase 2: reads for c3 (A47k1); MFMA c2 ----
#pragma unroll
    for (int i = 0; i < 4; ++i) aD[i] = *(const bf16x8*)(Ab + (aOff[4 + i] ^ 32));
    if (s1) { STAGE_B(2, b ^ 1, kt + 1); STAGE_B(3, b ^ 1, kt + 1); }
    asm volatile("" ::: "memory");
    __builtin_amdgcn_s_barrier();
    __builtin_amdgcn_s_setprio(1);
#pragma unroll
    for (int i = 0; i < 4; ++i)
#pragma unroll
      for (int nt = 0; nt < 4; ++nt)
        acc[i][nt] = __builtin_amdgcn_mfma_f32_16x16x32_bf16(aC[i], bk1[nt], acc[i][nt], 0, 0, 0);
    __builtin_amdgcn_s_setprio(0);
    __builtin_amdgcn_s_barrier();

    // ---- phase 3: stage tile kt+2 {A0,A2} into current buffer; MFMA c3 ----
    if (s2) { STAGE_A(0, b, kt + 2); STAGE_A(2, b, kt + 2); }
    asm volatile("" ::: "memory");
    __builtin_amdgcn_s_barrier();
    __builtin_amdgcn_s_setprio(1);
#pragma unroll
    for (int i = 0; i < 4; ++i)
#pragma unroll
      for (int nt = 0; nt < 4; ++nt)
        acc[4 + i][nt] = __builtin_amdgcn_mfma_f32_16x16x32_bf16(aD[i], bk1[nt], acc[4 + i][nt], 0, 0, 0);
    __builtin_amdgcn_s_setprio(0);

    // ---- boundary: counted wait (tile kt+1 landed; kt+2's pair stays out) ----
    if (s1) {
      if (s2) asm volatile("s_waitcnt vmcnt(2)" ::: "memory");
      else    asm volatile("s_waitcnt vmcnt(0)" ::: "memory");
      __builtin_amdgcn_s_barrier();
    }
  }
#undef STAGE_A
#undef STAGE_B

  // ---- epilogue ----
  // C/D layout: col = lane&15, row = quad*4 + reg  [verified m89/m91]
#pragma unroll
  for (int mt = 0; mt < 8; ++mt) {
#pragma unroll
    for (int nt = 0; nt < 4; ++nt) {
#pragma unroll
      for (int rg = 0; rg < 4; ++rg) {
        const int m = m0 + wr * 128 + mt * 16 + quad * 4 + rg;
        const int n = n0 + wc * 64 + nt * 16 + lrow;
        float v = acc[mt][nt][rg];
        const int p = n & 1;               // 0 = real component, 1 = imag

        if (MODE == 1) {
          const int cj = n & 1023;
          const int j = cj >> 1;
          const float bias = p ? (bx_im[region * 512 + j] + bh_im[region * 512 + j])
                               : (bx_re[region * 512 + j] + bh_re[region * 512 + j]);
          const float val = v + bias;
          if (region == 0) {               // z gate (bf16 store)
            zbuf[(size_t)m * 1024 + cj] = (bf16_t)fast_sigmoid(val);
          } else if (region == 1) {        // r gate -> rh = r * h (complex)
            float rv = fast_sigmoid(val);
            float ro = __shfl_xor(rv, 1, 64);
            float hp = p ? h_im[(size_t)m * 512 + j] : h_re[(size_t)m * 512 + j];
            float ho = __shfl_xor(hp, 1, 64);
            float rh = (p == 0) ? (rv * hp - ro * ho) : (ro * hp + rv * ho);
            A2[(size_t)m * 1024 + p * 512 + j] = (bf16_t)rh;
          } else {                         // px2 + bx2 + bh2 -> staged in d_out
            outbuf[(size_t)m * 1024 + cj] = val;
          }
        } else {
          // MODE 2: u = t + ph ; h_tilde = tanh(|u|)/|u| * u ; combine
          const int j = n >> 1;
          float tv = outbuf[(size_t)m * 1024 + n];
          float u = tv + v;
          float uo = __shfl_xor(u, 1, 64);
          float mag = sqrtf(u * u + uo * uo);
          float mm = fminf(mag, 20.0f);
          float e = __expf(2.0f * mm);
          float th = (e - 1.0f) / (e + 1.0f);
          float s = (mag == 0.0f) ? 0.0f : (th / mag);
          float hto = s * u;               // own component of h_tilde
          float htd = s * uo;              // other component
          float zv = (float)zbuf[(size_t)m * 1024 + n];
          float zo = __shfl_xor(zv, 1, 64);
          float hp = p ? h_im[(size_t)m * 512 + j] : h_re[(size_t)m * 512 + j];
          float ho = __shfl_xor(hp, 1, 64);
          float res;
          if (p == 0)
            res = (1.0f - zv) * hp + zo * ho + zv * hto - zo * htd;
          else
            res = (1.0f - zo) * hp - zv * ho + zo * hto + zv * htd;
          outbuf[(size_t)m * 1024 + n] = res;
        }
      }
    }
  }
}

// ---------------------------------------------------------------------------
extern "C" void kernel_launch(void* const* d_in, const int* in_sizes, int n_in,
                              void* d_out, int out_size, void* d_ws, size_t ws_size,
                              hipStream_t stream) {
  const float* x_re  = (const float*)d_in[0];
  const float* x_im  = (const float*)d_in[1];
  const float* h_re  = (const float*)d_in[2];
  const float* h_im  = (const float*)d_in[3];
  const float* Wx_re = (const float*)d_in[4];
  const float* Wx_im = (const float*)d_in[5];
  const float* Wh_re = (const float*)d_in[6];
  const float* Wh_im = (const float*)d_in[7];
  const float* bx_re = (const float*)d_in[8];
  const float* bx_im = (const float*)d_in[9];
  const float* bh_re = (const float*)d_in[10];
  const float* bh_im = (const float*)d_in[11];
  float* out = (float*)d_out;

  char* ws = (char*)d_ws;
  bf16_t* A_big = (bf16_t*)(ws);                         // 67108864 B
  bf16_t* W1t   = (bf16_t*)(ws + 67108864);              // 12582912 B
  bf16_t* W2t   = (bf16_t*)(ws + 79691776);              //  2097152 B
  bf16_t* A2    = (bf16_t*)(ws + 81788928);              // 33554432 B
  bf16_t* zbuf  = (bf16_t*)(ws + 115343360);             // 33554432 B  (end: 148897792)

  pack_A<<<32768, 256, 0, stream>>>(x_re, x_im, h_re, h_im, A_big);
  pack_W<<<6144, 256, 0, stream>>>(Wx_re, Wx_im, Wh_re, Wh_im, W1t, W2t);
  gemm_fused<1><<<768, 512, 0, stream>>>(A_big, W1t, 2048, 2048,
      zbuf, A2, out, h_re, h_im, bx_re, bx_im, bh_re, bh_im);
  gemm_fused<2><<<256, 512, 0, stream>>>(A2, W2t, 1024, 1024,
      zbuf, A2, out, h_re, h_im, bx_re, bx_im, bh_re, bh_im);
}

// Round 2
// 629.342 us; speedup vs baseline: 1.1641x; 1.0153x over previous
//
#include <hip/hip_runtime.h>
#include <hip/hip_bf16.h>

typedef __bf16 bf16_t;
typedef __bf16 bf16x8 __attribute__((ext_vector_type(8)));
typedef __bf16 bf16x4 __attribute__((ext_vector_type(4)));
typedef float f32x4 __attribute__((ext_vector_type(4)));

// ---------------------------------------------------------------------------
// Sizes (fixed): B = 16384, D = H = 512
//   A_big : [B][2048] bf16 = [x_re | x_im | h_re | h_im]
//   W1t   : [3072][2048] bf16 (B^T layout). Columns: [0,1024) z (K=2048),
//           [1024,2048) r (K=2048), [2048,3072) px2 (K=1024). re/im interleaved.
//   W2t   : [1024][1024] bf16, ph columns interleaved, K=1024 over [rh_re|rh_im]
//   A2    : [B][1024] bf16 = [rh_re | rh_im]
//   zbuf  : [B][1024] bf16 interleaved (z in [0,1]; bf16 quant <= 4e-3, safe)
//   t (= px2+bx2+bh2) staged fp32 in d_out, overwritten by final in GEMM2.
// ---------------------------------------------------------------------------

__device__ __forceinline__ void gl_lds16(const bf16_t* g, bf16_t* l) {
  __builtin_amdgcn_global_load_lds(
      (const __attribute__((address_space(1))) void*)g,
      (__attribute__((address_space(3))) void*)l, 16, 0, 0);
}

__device__ __forceinline__ float fast_sigmoid(float x) {
  return 1.0f / (1.0f + __expf(-x));
}

// ---------------------------------------------------------------------------
__global__ void pack_A(const float* __restrict__ x_re, const float* __restrict__ x_im,
                       const float* __restrict__ h_re, const float* __restrict__ h_im,
                       bf16_t* __restrict__ A) {
  int q = blockIdx.x * blockDim.x + threadIdx.x;   // 8388608 quads total
  int i4 = q << 2;
  int b = i4 >> 11;
  int k = i4 & 2047;
  int seg = k >> 9;
  int off = k & 511;
  const float* s = (seg == 0) ? x_re : (seg == 1) ? x_im : (seg == 2) ? h_re : h_im;
  const float4 v = *(const float4*)(s + (size_t)b * 512 + off);
  bf16x4 o = { (bf16_t)v.x, (bf16_t)v.y, (bf16_t)v.z, (bf16_t)v.w };
  *(bf16x4*)(A + (size_t)b * 2048 + k) = o;
}

// ---------------------------------------------------------------------------
__global__ void pack_W(const float* __restrict__ Wx_re, const float* __restrict__ Wx_im,
                       const float* __restrict__ Wh_re, const float* __restrict__ Wh_im,
                       bf16_t* __restrict__ W1t, bf16_t* __restrict__ W2t) {
  int q = blockIdx.x * blockDim.x + threadIdx.x;   // 1572864 quads total
  int n, k2, g, j, p;
  const float *Wre, *Wim;
  bf16_t* dst;
  if (q < 1048576) {                       // W1t rows [0,2048): z and r, k2 in [0,2048)
    n = q >> 9; k2 = (q & 511) << 2;
    g = n >> 10; j = (n & 1023) >> 1; p = n & 1;
    int pair = k2 >> 10;                   // 0: x-part (Wx), 1: h-part (Wh)
    Wre = pair ? Wh_re : Wx_re;
    Wim = pair ? Wh_im : Wx_im;
    dst = W1t + (size_t)n * 2048 + k2;
  } else if (q < 1048576 + 262144) {       // W1t rows [2048,3072): px2, k2 in [0,1024)
    int q2 = q - 1048576;
    n = 2048 + (q2 >> 8); k2 = (q2 & 255) << 2;
    g = 2; j = (n - 2048) >> 1; p = n & 1;
    Wre = Wx_re; Wim = Wx_im;
    dst = W1t + (size_t)n * 2048 + k2;
  } else {                                 // W2t rows [0,1024), k2 in [0,1024)
    int q3 = q - (1048576 + 262144);
    n = q3 >> 8; k2 = (q3 & 255) << 2;
    g = 2; j = n >> 1; p = n & 1;
    Wre = Wh_re; Wim = Wh_im;
    dst = W2t + (size_t)n * 1024 + k2;
  }
  int klocal = k2 & 1023;
  int half = klocal >> 9;                  // 0: real-operand half, 1: imag-operand half
  int off = klocal & 511;
  size_t sidx = ((size_t)g * 512 + j) * 512 + off;
  const float* s = (half == 0) ? (p ? Wim : Wre) : (p ? Wre : Wim);
  float sgn = (half == 1 && p == 0) ? -1.0f : 1.0f;
  float4 v = *(const float4*)(s + sidx);
  bf16x4 o = { (bf16_t)(sgn * v.x), (bf16_t)(sgn * v.y),
               (bf16_t)(sgn * v.z), (bf16_t)(sgn * v.w) };
  *(bf16x4*)dst = o;
}

// ---------------------------------------------------------------------------
// 256x256 tile, BK=64, 512 threads (8 waves, 2M x 4N; per-wave 128x64 output).
// 2 LDS buffers (128 KiB). Per K-tile: 4 MFMA clusters of 16, with fragment
// ds_reads issued one cluster early where possible, and ONLY 2 BARRIERS:
//   - mid-tile barrier (end of phase 2): needed before phase 3 pre-stages
//     tile kt+2's sweeps {A0,A2} into the CURRENT buffer. Readers of those
//     sweeps (aA phase 0, aC phase 1) are drained by their MFMA consumers
//     before any wave reaches the barrier; still-pending aD reads target
//     disjoint sweeps {1,3}.
//   - boundary vmcnt(2) + barrier: tile kt+1's 8 staging loads landed
//     (6 issued this tile + 2 pre-staged last tile); kt+2's pair stays in
//     flight (counted wait, never drain to 0 in steady state).
// All other staging targets the OTHER buffer (b^1), so intra-tile ds_reads
// race nothing -> no lockstep: waves skew freely and one wave's LDS drain
// hides under another's MFMA (the m97/m114 implicit-overlap mechanism).
// setprio(1) wraps each MFMA cluster. Swizzle: 16B-chunk c ^= (r&7), applied
// source-side for gl_lds and on the ds_read address (same involution).
// Grid decode: xcd-chunked bijective swizzle; each CU gets exactly one
// z (32 K-tiles) + one r (32) + one px2 (16) block in MODE 1.
template <int MODE>
__launch_bounds__(512, 2)
__global__ void gemm_fused(const bf16_t* __restrict__ A, const bf16_t* __restrict__ W,
                           int LDA, int LDW,
                           bf16_t* __restrict__ zbuf, bf16_t* __restrict__ A2,
                           float* __restrict__ outbuf,
                           const float* __restrict__ h_re, const float* __restrict__ h_im,
                           const float* __restrict__ bx_re, const float* __restrict__ bx_im,
                           const float* __restrict__ bh_re, const float* __restrict__ bh_im) {
  __shared__ __align__(16) bf16_t As[2][256 * 64];
  __shared__ __align__(16) bf16_t Bs[2][256 * 64];

  const int bid = blockIdx.x;
  const int xcd = bid & 7;
  const int idx = bid >> 3;               // MODE1: 0..95, MODE2: 0..31
  const int ntile = idx >> 3;             // MODE1: 0..11, MODE2: 0..3
  const int mtile = (xcd << 3) + (idx & 7);  // 0..63
  const int m0 = mtile * 256;
  const int n0 = ntile * 256;
  const int region = (MODE == 1) ? (ntile >> 2) : 0;    // 0:z 1:r 2:px2
  const int KEND = (MODE == 1) ? ((region < 2) ? 2048 : 1024) : 1024;
  const int nKT = KEND >> 6;              // K-tiles of 64

  const int tid = threadIdx.x;
  const int lane = tid & 63;
  const int w = tid >> 6;                 // 0..7
  const int wr = w >> 2;                  // 0..1 (M)
  const int wc = w & 3;                   // 0..3 (N)

  // staging: sweep s covers rows [64s, 64s+64); thread -> (row rb, chunk cc)
  const int rb = tid >> 3;                // 0..63
  const int cc = tid & 7;                 // 16B chunk within 128B row
  const int cs = cc ^ (rb & 7);           // source-side swizzle
  const bf16_t* Ag = A + (size_t)(m0 + rb) * LDA + cs * 8;
  const bf16_t* Wg = W + (size_t)(n0 + rb) * LDW + cs * 8;

#define STAGE_A(s, bufi, kt2) \
  gl_lds16(Ag + (size_t)(s) * 64 * LDA + (kt2) * 64, &As[bufi][tid * 8 + (s) * 4096])
#define STAGE_B(s, bufi, kt2) \
  gl_lds16(Wg + (size_t)(s) * 64 * LDW + (kt2) * 64, &Bs[bufi][tid * 8 + (s) * 4096])

  const int quad = lane >> 4, lrow = lane & 15;
  int aOff[8], bOff[4];                   // kk0 offsets; kk1 = off ^ 32
#pragma unroll
  for (int mt = 0; mt < 8; ++mt) {
    const int r = wr * 128 + mt * 16 + lrow;
    aOff[mt] = r * 64 + ((quad ^ (r & 7)) << 3);
  }
#pragma unroll
  for (int nt = 0; nt < 4; ++nt) {
    const int r = wc * 64 + nt * 16 + lrow;
    bOff[nt] = r * 64 + ((quad ^ (r & 7)) << 3);
  }

  f32x4 acc[8][4] = {};

  // prologue: tile 0 fully (8 loads, oldest) + tile 1 {A0,A2} (2 loads)
#pragma unroll
  for (int s = 0; s < 4; ++s) STAGE_A(s, 0, 0);
#pragma unroll
  for (int s = 0; s < 4; ++s) STAGE_B(s, 0, 0);
  STAGE_A(0, 1, 1);
  STAGE_A(2, 1, 1);
  asm volatile("s_waitcnt vmcnt(2)" ::: "memory");
  __builtin_amdgcn_s_barrier();

  for (int kt = 0; kt < nKT; ++kt) {
    const int b = kt & 1;
    const bf16_t* Ab = As[b];
    const bf16_t* Bb = Bs[b];
    const bool s1 = (kt + 1 < nKT);
    const bool s2 = (kt + 2 < nKT);

    bf16x8 bk0[4], bk1[4], aA[4], aB[4], aC[4], aD[4];

    // ---- phase 0: reads for c0 (A03k0 + Bk0) and c1 (A47k0); MFMA c0 ----
#pragma unroll
    for (int nt = 0; nt < 4; ++nt) bk0[nt] = *(const bf16x8*)(Bb + bOff[nt]);
#pragma unroll
    for (int i = 0; i < 4; ++i) aA[i] = *(const bf16x8*)(Ab + aOff[i]);
#pragma unroll
    for (int i = 0; i < 4; ++i) aB[i] = *(const bf16x8*)(Ab + aOff[4 + i]);
    if (s1) { STAGE_A(1, b ^ 1, kt + 1); STAGE_A(3, b ^ 1, kt + 1); }
    __builtin_amdgcn_s_setprio(1);
#pragma unroll
    for (int i = 0; i < 4; ++i)
#pragma unroll
      for (int nt = 0; nt < 4; ++nt)
        acc[i][nt] = __builtin_amdgcn_mfma_f32_16x16x32_bf16(aA[i], bk0[nt], acc[i][nt], 0, 0, 0);
    __builtin_amdgcn_s_setprio(0);

    // ---- phase 1: reads for c2 (A03k1 + Bk1); MFMA c1 ----
#pragma unroll
    for (int i = 0; i < 4; ++i) aC[i] = *(const bf16x8*)(Ab + (aOff[i] ^ 32));
#pragma unroll
    for (int nt = 0; nt < 4; ++nt) bk1[nt] = *(const bf16x8*)(Bb + (bOff[nt] ^ 32));
    if (s1) { STAGE_B(0, b ^ 1, kt + 1); STAGE_B(1, b ^ 1, kt + 1); }
    __builtin_amdgcn_s_setprio(1);
#pragma unroll
    for (int i = 0; i < 4; ++i)
#pragma unroll
      for (int nt = 0; nt < 4; ++nt)
        acc[4 + i][nt] = __builtin_amdgcn_mfma_f32_16x16x32_bf16(aB[i], bk0[nt], acc[4 + i][nt], 0, 0, 0);
    __builtin_amdgcn_s_setprio(0);

    // ---- phase 2: reads for c3 (A47k1); MFMA c2 ----
#pragma unroll
    for (int i = 0; i < 4; ++i) aD[i] = *(const bf16x8*)(Ab + (aOff[4 + i] ^ 32));
    if (s1) { STAGE_B(2, b ^ 1, kt + 1); STAGE_B(3, b ^ 1, kt + 1); }
    __builtin_amdgcn_s_setprio(1);
#pragma unroll
    for (int i = 0; i < 4; ++i)
#pragma unroll
      for (int nt = 0; nt < 4; ++nt)
        acc[i][nt] = __builtin_amdgcn_mfma_f32_16x16x32_bf16(aC[i], bk1[nt], acc[i][nt], 0, 0, 0);
    __builtin_amdgcn_s_setprio(0);

    // ---- mid-tile barrier: phase 3 writes CURRENT buffer sweeps {0,2} ----
    asm volatile("" ::: "memory");
    __builtin_amdgcn_s_barrier();

    // ---- phase 3: pre-stage tile kt+2 {A0,A2} into current buffer; MFMA c3 ----
    if (s2) { STAGE_A(0, b, kt + 2); STAGE_A(2, b, kt + 2); }
    __builtin_amdgcn_s_setprio(1);
#pragma unroll
    for (int i = 0; i < 4; ++i)
#pragma unroll
      for (int nt = 0; nt < 4; ++nt)
        acc[4 + i][nt] = __builtin_amdgcn_mfma_f32_16x16x32_bf16(aD[i], bk1[nt], acc[4 + i][nt], 0, 0, 0);
    __builtin_amdgcn_s_setprio(0);

    // ---- boundary: counted wait (tile kt+1 landed; kt+2's pair stays out) ----
    if (s1) {
      if (s2) asm volatile("s_waitcnt vmcnt(2)" ::: "memory");
      else    asm volatile("s_waitcnt vmcnt(0)" ::: "memory");
      asm volatile("" ::: "memory");
      __builtin_amdgcn_s_barrier();
    }
  }
#undef STAGE_A
#undef STAGE_B

  // ---- epilogue ----
  // C/D layout: col = lane&15, row = quad*4 + reg  [verified m89/m91]
#pragma unroll
  for (int mt = 0; mt < 8; ++mt) {
#pragma unroll
    for (int nt = 0; nt < 4; ++nt) {
#pragma unroll
      for (int rg = 0; rg < 4; ++rg) {
        const int m = m0 + wr * 128 + mt * 16 + quad * 4 + rg;
        const int n = n0 + wc * 64 + nt * 16 + lrow;
        float v = acc[mt][nt][rg];
        const int p = n & 1;               // 0 = real component, 1 = imag

        if (MODE == 1) {
          const int cj = n & 1023;
          const int j = cj >> 1;
          const float bias = p ? (bx_im[region * 512 + j] + bh_im[region * 512 + j])
                               : (bx_re[region * 512 + j] + bh_re[region * 512 + j]);
          const float val = v + bias;
          if (region == 0) {               // z gate (bf16 store)
            zbuf[(size_t)m * 1024 + cj] = (bf16_t)fast_sigmoid(val);
          } else if (region == 1) {        // r gate -> rh = r * h (complex)
            float rv = fast_sigmoid(val);
            float ro = __shfl_xor(rv, 1, 64);
            float hp = p ? h_im[(size_t)m * 512 + j] : h_re[(size_t)m * 512 + j];
            float ho = __shfl_xor(hp, 1, 64);
            float rh = (p == 0) ? (rv * hp - ro * ho) : (ro * hp + rv * ho);
            A2[(size_t)m * 1024 + p * 512 + j] = (bf16_t)rh;
          } else {                         // px2 + bx2 + bh2 -> staged in d_out
            outbuf[(size_t)m * 1024 + cj] = val;
          }
        } else {
          // MODE 2: u = t + ph ; h_tilde = tanh(|u|)/|u| * u ; combine
          const int j = n >> 1;
          float tv = outbuf[(size_t)m * 1024 + n];
          float u = tv + v;
          float uo = __shfl_xor(u, 1, 64);
          float mag = sqrtf(u * u + uo * uo);
          float mm = fminf(mag, 20.0f);
          float e = __expf(2.0f * mm);
          float th = (e - 1.0f) / (e + 1.0f);
          float s = (mag == 0.0f) ? 0.0f : (th / mag);
          float hto = s * u;               // own component of h_tilde
          float htd = s * uo;              // other component
          float zv = (float)zbuf[(size_t)m * 1024 + n];
          float zo = __shfl_xor(zv, 1, 64);
          float hp = p ? h_im[(size_t)m * 512 + j] : h_re[(size_t)m * 512 + j];
          float ho = __shfl_xor(hp, 1, 64);
          float res;
          if (p == 0)
            res = (1.0f - zv) * hp + zo * ho + zv * hto - zo * htd;
          else
            res = (1.0f - zo) * hp - zv * ho + zo * hto + zv * htd;
          outbuf[(size_t)m * 1024 + n] = res;
        }
      }
    }
  }
}

// ---------------------------------------------------------------------------
extern "C" void kernel_launch(void* const* d_in, const int* in_sizes, int n_in,
                              void* d_out, int out_size, void* d_ws, size_t ws_size,
                              hipStream_t stream) {
  const float* x_re  = (const float*)d_in[0];
  const float* x_im  = (const float*)d_in[1];
  const float* h_re  = (const float*)d_in[2];
  const float* h_im  = (const float*)d_in[3];
  const float* Wx_re = (const float*)d_in[4];
  const float* Wx_im = (const float*)d_in[5];
  const float* Wh_re = (const float*)d_in[6];
  const float* Wh_im = (const float*)d_in[7];
  const float* bx_re = (const float*)d_in[8];
  const float* bx_im = (const float*)d_in[9];
  const float* bh_re = (const float*)d_in[10];
  const float* bh_im = (const float*)d_in[11];
  float* out = (float*)d_out;

  char* ws = (char*)d_ws;
  bf16_t* A_big = (bf16_t*)(ws);                         // 67108864 B
  bf16_t* W1t   = (bf16_t*)(ws + 67108864);              // 12582912 B
  bf16_t* W2t   = (bf16_t*)(ws + 79691776);              //  2097152 B
  bf16_t* A2    = (bf16_t*)(ws + 81788928);              // 33554432 B
  bf16_t* zbuf  = (bf16_t*)(ws + 115343360);             // 33554432 B  (end: 148897792)

  pack_A<<<32768, 256, 0, stream>>>(x_re, x_im, h_re, h_im, A_big);
  pack_W<<<6144, 256, 0, stream>>>(Wx_re, Wx_im, Wh_re, Wh_im, W1t, W2t);
  gemm_fused<1><<<768, 512, 0, stream>>>(A_big, W1t, 2048, 2048,
      zbuf, A2, out, h_re, h_im, bx_re, bx_im, bh_re, bh_im);
  gemm_fused<2><<<256, 512, 0, stream>>>(A2, W2t, 1024, 1024,
      zbuf, A2, out, h_re, h_im, bx_re, bx_im, bh_re, bh_im);
}